// Round 3
// baseline (543.630 us; speedup 1.0000x reference)
//
#include <hip/hip_runtime.h>

typedef _Float16 f16;
typedef _Float16 f16x4 __attribute__((ext_vector_type(4)));
typedef _Float16 f16x8 __attribute__((ext_vector_type(8)));
typedef float    f32x4 __attribute__((ext_vector_type(4)));

#define B_  2
#define C_  512
#define N_  2048
#define H_  8
#define DK_ 64
#define BH_ (B_*H_)
#define NIT 18

// ---------------- Kernel A: QKV GEMM (fp32 VALU, 128x128 tile, 8x8/thread) ----
// mat 0/1 (Q,K): store (b,h,n,d) f16.  mat 2 (V): store transposed (b,h,d,n) f16.
__global__ __launch_bounds__(256) void qkv_gemm(
    const float* __restrict__ x,
    const float* __restrict__ Wq, const float* __restrict__ Wk, const float* __restrict__ Wv,
    const float* __restrict__ bq, const float* __restrict__ bk, const float* __restrict__ bv,
    f16* __restrict__ q16, f16* __restrict__ k16, f16* __restrict__ vT16)
{
  const int nt = blockIdx.x;      // 0..15  (n tiles of 128; N=2048)
  const int ct = blockIdx.y;      // 0..3   (c tiles of 128)
  const int z  = blockIdx.z;      // 0..5   (b*3 + mat)
  const int b = z / 3, mat = z % 3;
  const float* W    = (mat == 0) ? Wq : (mat == 1) ? Wk : Wv;
  const float* bias = (mat == 0) ? bq : (mat == 1) ? bk : bv;

  const int n0 = nt * 128, c0 = ct * 128;
  __shared__ float xs[16][132];   // x tile [m][n]
  __shared__ float ws[16][132];   // W tile transposed [m][c]
  const int t = threadIdx.x;
  const float* xb = x + (size_t)b * C_ * N_;

  float acc[8][8];
  #pragma unroll
  for (int i = 0; i < 8; ++i)
    #pragma unroll
    for (int j = 0; j < 8; ++j) acc[i][j] = 0.f;

  #pragma unroll 1
  for (int m0 = 0; m0 < C_; m0 += 16) {
    #pragma unroll
    for (int u = 0; u < 2; ++u) {            // load x[m0..+15][n0..+127]
      int idx = t + u * 256;
      int r = idx >> 5, col = (idx & 31) << 2;
      *(float4*)&xs[r][col] = *(const float4*)(xb + (size_t)(m0 + r) * N_ + n0 + col);
    }
    #pragma unroll
    for (int u = 0; u < 2; ++u) {            // load W[c0..+127][m0..+15] transposed
      int idx = t + u * 256;
      int cc = idx >> 2, mq = idx & 3;
      float4 wv = *(const float4*)(W + (size_t)(c0 + cc) * C_ + m0 + mq * 4);
      ws[mq*4+0][cc] = wv.x; ws[mq*4+1][cc] = wv.y;
      ws[mq*4+2][cc] = wv.z; ws[mq*4+3][cc] = wv.w;
    }
    __syncthreads();
    const int tn = t & 15, tc = t >> 4;
    #pragma unroll
    for (int mm = 0; mm < 16; ++mm) {
      float a[8], bb[8];
      *(float4*)(a)    = *(const float4*)&xs[mm][tn*8];
      *(float4*)(a+4)  = *(const float4*)&xs[mm][tn*8+4];
      *(float4*)(bb)   = *(const float4*)&ws[mm][tc*8];
      *(float4*)(bb+4) = *(const float4*)&ws[mm][tc*8+4];
      #pragma unroll
      for (int i = 0; i < 8; ++i)
        #pragma unroll
        for (int j = 0; j < 8; ++j)
          acc[i][j] = fmaf(a[i], bb[j], acc[i][j]);
    }
    __syncthreads();
  }

  const int tn = t & 15, tc = t >> 4;
  if (mat == 2) {
    // V transposed: vT[(b*512 + c)*2048 + n], pack 8 consecutive n per store.
    #pragma unroll
    for (int j = 0; j < 8; ++j) {
      const int cfull = c0 + tc * 8 + j;
      const float bb = bias[cfull];
      f16x8 pk;
      #pragma unroll
      for (int i = 0; i < 8; ++i) pk[i] = (f16)(acc[i][j] + bb);
      *(f16x8*)(vT16 + ((size_t)b * C_ + cfull) * N_ + n0 + tn * 8) = pk;
    }
  } else {
    f16* out = (mat == 0) ? q16 : k16;
    #pragma unroll
    for (int i = 0; i < 8; ++i) {
      const size_t n = (size_t)n0 + tn * 8 + i;
      #pragma unroll
      for (int jq = 0; jq < 8; jq += 4) {
        int c = c0 + tc * 8 + jq;
        int h = c >> 6, d = c & 63;
        f16x4 pk;
        #pragma unroll
        for (int u = 0; u < 4; ++u) pk[u] = (f16)(acc[i][jq + u] + bias[c + u]);
        *(f16x4*)(out + ((size_t)(b * H_ + h) * N_ + n) * DK_ + d) = pk;
      }
    }
  }
}

// ---------------- Kernel B: fused energy + entmax1.5 (Newton) + PV ------------
// block: 256 thr = 4 waves. 16 q-rows/block, wave w owns j-strip [512w,512w+512).
__global__ __launch_bounds__(256, 1) void attn(
    const f16* __restrict__ q16, const f16* __restrict__ k16,
    const f16* __restrict__ vT16, float* __restrict__ o)
{
  const int bh = blockIdx.y;
  const int n0 = blockIdx.x * 16;
  const int t = threadIdx.x;
  const int w = t >> 6, lane = t & 63;
  const int c = lane & 15, g = lane >> 4;

  __shared__ f16  p_lds[16 * 2056];     // [row][j], row stride 2056 (pad 8)
  __shared__ float red[4][16][2];       // cross-wave scratch

  const f16* Q  = q16  + (size_t)bh * N_ * DK_;
  const f16* K  = k16  + (size_t)bh * N_ * DK_;
  const f16* VT = vT16 + (size_t)bh * DK_ * N_;

  // A-frags (Q rows n0..n0+15): lane row = c, k-chunk = 8g (+32 for kstep 1)
  f16x8 qa0 = *(const f16x8*)(Q + (size_t)(n0 + c) * DK_ + 8 * g);
  f16x8 qa1 = *(const f16x8*)(Q + (size_t)(n0 + c) * DK_ + 32 + 8 * g);

  const int jbase = w * 512;
  f32x4 acc[32];
  #pragma unroll
  for (int T = 0; T < 32; ++T) acc[T] = (f32x4){0.f, 0.f, 0.f, 0.f};

  // ---- energy: s = (q.k)  (scale 1/16 applied later) ----
  #pragma unroll
  for (int T = 0; T < 32; ++T) {
    const f16* kp = K + (size_t)(jbase + 16 * T + c) * DK_ + 8 * g;
    f16x8 kb0 = *(const f16x8*)(kp);
    f16x8 kb1 = *(const f16x8*)(kp + 32);
    acc[T] = __builtin_amdgcn_mfma_f32_16x16x32_f16(qa0, kb0, acc[T], 0, 0, 0);
    acc[T] = __builtin_amdgcn_mfma_f32_16x16x32_f16(qa1, kb1, acc[T], 0, 0, 0);
  }

  // ---- row max (over raw acc; scaling is monotone) ----
  float m[4] = {-1e30f, -1e30f, -1e30f, -1e30f};
  #pragma unroll
  for (int T = 0; T < 32; ++T)
    #pragma unroll
    for (int e = 0; e < 4; ++e) m[e] = fmaxf(m[e], acc[T][e]);
  #pragma unroll
  for (int dm = 1; dm <= 8; dm <<= 1)
    #pragma unroll
    for (int e = 0; e < 4; ++e) m[e] = fmaxf(m[e], __shfl_xor(m[e], dm, 64));
  if (c == 0) {
    #pragma unroll
    for (int e = 0; e < 4; ++e) red[w][4 * g + e][0] = m[e];
  }
  __syncthreads();
  #pragma unroll
  for (int e = 0; e < 4; ++e) {
    float mm_ = red[0][4 * g + e][0];
    mm_ = fmaxf(mm_, red[1][4 * g + e][0]);
    mm_ = fmaxf(mm_, red[2][4 * g + e][0]);
    mm_ = fmaxf(mm_, red[3][4 * g + e][0]);
    m[e] = mm_;
  }
  __syncthreads();

  // ---- z' = acc/16 - max/16  (reference: z = energy/2 = dot/16, shift by max) ----
  float ms[4];
  #pragma unroll
  for (int e = 0; e < 4; ++e) ms[e] = m[e] * 0.0625f;
  #pragma unroll
  for (int T = 0; T < 32; ++T)
    #pragma unroll
    for (int e = 0; e < 4; ++e) acc[T][e] = fmaf(acc[T][e], 0.0625f, -ms[e]);

  // ---- Newton on f(tau) = sum clip(z'-tau,0)^2 - 1, from tau=-1 (monotone) ----
  float tau[4] = {-1.f, -1.f, -1.f, -1.f};
  #pragma unroll 1
  for (int it = 0; it < NIT; ++it) {
    float S1[4] = {0.f, 0.f, 0.f, 0.f}, S2[4] = {0.f, 0.f, 0.f, 0.f};
    #pragma unroll
    for (int T = 0; T < 32; ++T)
      #pragma unroll
      for (int e = 0; e < 4; ++e) {
        float d_ = fmaxf(acc[T][e] - tau[e], 0.f);
        S1[e] += d_;
        S2[e] = fmaf(d_, d_, S2[e]);
      }
    #pragma unroll
    for (int dm = 1; dm <= 8; dm <<= 1)
      #pragma unroll
      for (int e = 0; e < 4; ++e) {
        S1[e] += __shfl_xor(S1[e], dm, 64);
        S2[e] += __shfl_xor(S2[e], dm, 64);
      }
    if (c == 0) {
      #pragma unroll
      for (int e = 0; e < 4; ++e) { red[w][4*g+e][0] = S1[e]; red[w][4*g+e][1] = S2[e]; }
    }
    __syncthreads();
    #pragma unroll
    for (int e = 0; e < 4; ++e) {
      float s1 = red[0][4*g+e][0] + red[1][4*g+e][0] + red[2][4*g+e][0] + red[3][4*g+e][0];
      float s2 = red[0][4*g+e][1] + red[1][4*g+e][1] + red[2][4*g+e][1] + red[3][4*g+e][1];
      tau[e] += (s2 - 1.f) / (2.f * s1 + 1e-20f);
    }
    __syncthreads();
  }

  // ---- p = clip(z'-tau,0)^2 -> p_lds[row][j] (f16) ----
  #pragma unroll
  for (int T = 0; T < 32; ++T)
    #pragma unroll
    for (int e = 0; e < 4; ++e) {
      float d_ = fmaxf(acc[T][e] - tau[e], 0.f);
      p_lds[(4 * g + e) * 2056 + jbase + 16 * T + c] = (f16)(d_ * d_);
    }
  __syncthreads();

  // ---- PV: wave w owns d-cols [16w,16w+16), all j ----
  f32x4 oacc = (f32x4){0.f, 0.f, 0.f, 0.f};
  #pragma unroll
  for (int T = 0; T < 64; ++T) {
    f16x8 pa = *(const f16x8*)&p_lds[c * 2056 + 32 * T + 8 * g];
    f16x8 vb = *(const f16x8*)(VT + (size_t)(16 * w + c) * N_ + 32 * T + 8 * g);
    oacc = __builtin_amdgcn_mfma_f32_16x16x32_f16(pa, vb, oacc, 0, 0, 0);
  }
  const int b = bh >> 3, h = bh & 7;
  #pragma unroll
  for (int e = 0; e < 4; ++e)
    o[((size_t)b * N_ + n0 + 4 * g + e) * C_ + h * 64 + 16 * w + c] = oacc[e];
}

// ---------------- Kernel C: LayerNorm(o) + residual x^T (in place on d_out) ---
__global__ __launch_bounds__(256) void ln_res(
    const float* __restrict__ o, const float* __restrict__ x,
    const float* __restrict__ a2, const float* __restrict__ b2,
    float* __restrict__ out)
{
  const int row = blockIdx.x * 4 + (threadIdx.x >> 6);  // 0..4095
  const int lane = threadIdx.x & 63;
  const int b = row >> 11, n = row & (N_ - 1);
  const float* orow = o + (size_t)row * C_;
  const int c0 = lane * 8;

  float v[8];
  *(float4*)(v)     = *(const float4*)(orow + c0);
  *(float4*)(v + 4) = *(const float4*)(orow + c0 + 4);
  float s = 0.f, ss = 0.f;
  #pragma unroll
  for (int i = 0; i < 8; ++i) { s += v[i]; ss = fmaf(v[i], v[i], ss); }
  #pragma unroll
  for (int dm = 1; dm <= 32; dm <<= 1) {
    s  += __shfl_xor(s, dm, 64);
    ss += __shfl_xor(ss, dm, 64);
  }
  const float mean = s * (1.f / C_);
  float var = (ss - (float)C_ * mean * mean) * (1.f / (C_ - 1));
  var = fmaxf(var, 0.f);
  const float rd = 1.f / (sqrtf(var) + 1e-6f);

  float av[8], bv[8], res[8];
  *(float4*)(av)     = *(const float4*)(a2 + c0);
  *(float4*)(av + 4) = *(const float4*)(a2 + c0 + 4);
  *(float4*)(bv)     = *(const float4*)(b2 + c0);
  *(float4*)(bv + 4) = *(const float4*)(b2 + c0 + 4);
  #pragma unroll
  for (int i = 0; i < 8; ++i)
    res[i] = x[((size_t)b * C_ + c0 + i) * N_ + n];

  float r[8];
  #pragma unroll
  for (int i = 0; i < 8; ++i)
    r[i] = av[i] * (v[i] - mean) * rd + bv[i] + res[i];
  float* orow_out = out + (size_t)row * C_;
  *(float4*)(orow_out + c0)     = *(float4*)(r);
  *(float4*)(orow_out + c0 + 4) = *(float4*)(r + 4);
}

// ---------------- launch ------------------------------------------------------
extern "C" void kernel_launch(void* const* d_in, const int* in_sizes, int n_in,
                              void* d_out, int out_size, void* d_ws, size_t ws_size,
                              hipStream_t stream)
{
  const float* x  = (const float*)d_in[0];
  const float* Wq = (const float*)d_in[1];
  const float* bq = (const float*)d_in[2];
  const float* Wk = (const float*)d_in[3];
  const float* bk = (const float*)d_in[4];
  const float* Wv = (const float*)d_in[5];
  const float* bv = (const float*)d_in[6];
  const float* a2 = (const float*)d_in[7];
  const float* b2 = (const float*)d_in[8];

  const size_t HEADSZ = (size_t)BH_ * N_ * DK_;  // 2,097,152 elements
  f16* q16  = (f16*)d_ws;                        // 4 MB
  f16* k16  = q16 + HEADSZ;                      // 4 MB
  f16* vT16 = k16 + HEADSZ;                      // 4 MB  (total ws = 12 MB)
  float* o  = (float*)d_out;                     // fp32 o lives in d_out

  // N tiles: 2048/128 = 16 (was 32 -> OOB fault)
  qkv_gemm<<<dim3(16, 4, 6), 256, 0, stream>>>(x, Wq, Wk, Wv, bq, bk, bv, q16, k16, vT16);
  attn    <<<dim3(N_ / 16, BH_), 256, 0, stream>>>(q16, k16, vT16, o);
  ln_res  <<<dim3(1024), 256, 0, stream>>>(o, x, a2, b2, (float*)d_out);
}

// Round 5
// 283.722 us; speedup vs baseline: 1.9161x; 1.9161x over previous
//
#include <hip/hip_runtime.h>

typedef _Float16 f16;
typedef _Float16 f16x2 __attribute__((ext_vector_type(2)));
typedef _Float16 f16x4 __attribute__((ext_vector_type(4)));
typedef _Float16 f16x8 __attribute__((ext_vector_type(8)));
typedef float    f32x4 __attribute__((ext_vector_type(4)));

#define B_  2
#define C_  512
#define N_  2048
#define H_  8
#define DK_ 64
#define BH_ 16
#define NIT 12

static __device__ __forceinline__ f16x2 cvt_pk(float a, float b) {
  return __builtin_bit_cast(f16x2, __builtin_amdgcn_cvt_pkrtz(a, b));
}

#if defined(__has_builtin)
#if __has_builtin(__builtin_amdgcn_fdot2)
#define FDOT2(a,b,c) __builtin_amdgcn_fdot2((a),(b),(c),false)
#endif
#endif
#ifndef FDOT2
static __device__ __forceinline__ float FDOT2(f16x2 a, f16x2 b, float c) {
  return c + (float)a[0]*(float)b[0] + (float)a[1]*(float)b[1];
}
#endif

#define MFMA16(a,b,acc) __builtin_amdgcn_mfma_f32_16x16x32_f16((a),(b),(acc),0,0,0)

// ---------------- prep_x: x (b,m,n) fp32 -> xT16 (b,n,m) f16 ------------------
__global__ __launch_bounds__(256) void prep_x(const float* __restrict__ x,
                                              f16* __restrict__ xT)
{
  const int nt = blockIdx.x, mt = blockIdx.y, b = blockIdx.z;
  const int n0 = nt * 64, m0 = mt * 64;
  __shared__ float tile[64][65];
  const int t = threadIdx.x;
  {
    const int ml = t >> 2, nc = (t & 3) * 16;
    const float* src = x + ((size_t)(b * C_ + m0 + ml)) * N_ + n0 + nc;
    *(float4*)&tile[ml][nc]      = *(const float4*)(src);
    *(float4*)&tile[ml][nc + 4]  = *(const float4*)(src + 4);
    *(float4*)&tile[ml][nc + 8]  = *(const float4*)(src + 8);
    *(float4*)&tile[ml][nc + 12] = *(const float4*)(src + 12);
  }
  __syncthreads();
  {
    const int nl = t >> 2, mc = (t & 3) * 16;
    f16x8 o0, o1;
    #pragma unroll
    for (int i = 0; i < 8; ++i) {
      o0[i] = (f16)tile[mc + i][nl];
      o1[i] = (f16)tile[mc + 8 + i][nl];
    }
    f16* dst = xT + ((size_t)(b * N_ + n0 + nl)) * C_ + m0 + mc;
    *(f16x8*)(dst)     = o0;
    *(f16x8*)(dst + 8) = o1;
  }
}

// ---------------- wconv: W (c,m) fp32 -> f16, 3 matrices ----------------------
__global__ __launch_bounds__(256) void wconv(
    const float* __restrict__ Wq, const float* __restrict__ Wk,
    const float* __restrict__ Wv, f16* __restrict__ W16)
{
  const int mat = blockIdx.y;
  const float* W = (mat == 0) ? Wq : (mat == 1) ? Wk : Wv;
  const int idx = (blockIdx.x * 256 + threadIdx.x) * 8;
  float4 u0 = *(const float4*)(W + idx);
  float4 u1 = *(const float4*)(W + idx + 4);
  f16x8 o;
  o[0]=(f16)u0.x; o[1]=(f16)u0.y; o[2]=(f16)u0.z; o[3]=(f16)u0.w;
  o[4]=(f16)u1.x; o[5]=(f16)u1.y; o[6]=(f16)u1.z; o[7]=(f16)u1.w;
  *(f16x8*)(W16 + (size_t)mat * C_ * C_ + idx) = o;
}

// ---------------- qkv_mfma: 64n x 64c block, 4 waves, K=512, no LDS -----------
// q16 pre-scaled by 1/16 (folds energy scale). V stored transposed (b,c,n).
__global__ __launch_bounds__(256, 4) void qkv_mfma(
    const f16* __restrict__ xT, const f16* __restrict__ W16,
    const float* __restrict__ bq, const float* __restrict__ bk,
    const float* __restrict__ bv,
    f16* __restrict__ q16, f16* __restrict__ k16, f16* __restrict__ vT16)
{
  const int nt = blockIdx.x, ctb = blockIdx.y, z = blockIdx.z;
  const int b = z / 3, mat = z % 3;
  const float* bias = (mat == 0) ? bq : (mat == 1) ? bk : bv;
  const f16* Wm = W16 + (size_t)mat * C_ * C_;
  const int t = threadIdx.x, w = t >> 6, lane = t & 63;
  const int c = lane & 15, g = lane >> 4;

  const int nA = nt * 64 + w * 16 + c;             // A-frag row (load)
  const f16* ap = xT + (size_t)(b * N_ + nA) * C_ + 8 * g;

  f32x4 acc[4] = {};
  #pragma unroll
  for (int ki = 0; ki < 16; ++ki) {
    f16x8 a = *(const f16x8*)(ap + 32 * ki);
    #pragma unroll
    for (int ct = 0; ct < 4; ++ct) {
      const int ccol = ctb * 64 + ct * 16 + c;
      f16x8 bb = *(const f16x8*)(Wm + (size_t)ccol * C_ + 32 * ki + 8 * g);
      acc[ct] = MFMA16(a, bb, acc[ct]);
    }
  }

  const int nOut = nt * 64 + w * 16 + 4 * g;       // + e
  #pragma unroll
  for (int ct = 0; ct < 4; ++ct) {
    const int ccol = ctb * 64 + ct * 16 + c;
    const float bb = bias[ccol];
    if (mat == 2) {
      f16x4 pk;
      #pragma unroll
      for (int e = 0; e < 4; ++e) pk[e] = (f16)(acc[ct][e] + bb);
      *(f16x4*)(vT16 + ((size_t)(b * C_ + ccol)) * N_ + nOut) = pk;
    } else {
      const int h = ccol >> 6, d = ccol & 63;
      f16* out = (mat == 0) ? q16 : k16;
      const float sc = (mat == 0) ? 0.0625f : 1.0f;
      #pragma unroll
      for (int e = 0; e < 4; ++e)
        out[((size_t)((b * H_ + h) * N_ + nOut + e)) * DK_ + d] =
            (f16)((acc[ct][e] + bb) * sc);
    }
  }
}

// ---------------- attn: energy(MFMA) + packed-f16 Newton entmax1.5 + PV -------
// 16 q-rows/block, 4 waves x 512-j strips. z kept as 64 f16x2 regs (j, j+16).
__global__ __launch_bounds__(256, 4) void attn(
    const f16* __restrict__ q16, const f16* __restrict__ k16,
    const f16* __restrict__ vT16, float* __restrict__ o)
{
  const int bh = blockIdx.y;
  const int n0 = blockIdx.x * 16;
  const int t = threadIdx.x;
  const int w = t >> 6, lane = t & 63;
  const int c = lane & 15, g = lane >> 4;

  __shared__ f16 p_lds[16 * 1032];        // [row][j-half], pad 8
  __shared__ float red[2][4][16][2];      // dbuf cross-wave scratch

  const f16* Q  = q16  + (size_t)bh * N_ * DK_;
  const f16* K  = k16  + (size_t)bh * N_ * DK_;
  const f16* VT = vT16 + (size_t)bh * DK_ * N_;

  f16x8 qa0 = *(const f16x8*)(Q + (size_t)(n0 + c) * DK_ + 8 * g);
  f16x8 qa1 = *(const f16x8*)(Q + (size_t)(n0 + c) * DK_ + 32 + 8 * g);

  const int jbase = w * 512;

  // ---- energy -> z2 f16 pairs (z = q.k/16 via pre-scaled q) ----
  f16x2 z2[64];
  #pragma unroll
  for (int tt = 0; tt < 16; ++tt) {
    const f16* kp0 = K + (size_t)(jbase + 32 * tt + c) * DK_ + 8 * g;
    f16x8 kb00 = *(const f16x8*)(kp0);
    f16x8 kb01 = *(const f16x8*)(kp0 + 32);
    f16x8 kb10 = *(const f16x8*)(kp0 + 16 * DK_);
    f16x8 kb11 = *(const f16x8*)(kp0 + 16 * DK_ + 32);
    f32x4 a0 = {}, a1 = {};
    a0 = MFMA16(qa0, kb00, a0);
    a0 = MFMA16(qa1, kb01, a0);
    a1 = MFMA16(qa0, kb10, a1);
    a1 = MFMA16(qa1, kb11, a1);
    #pragma unroll
    for (int e = 0; e < 4; ++e)
      z2[tt * 4 + e] = cvt_pk(a0[e], a1[e]);
  }

  // ---- row max ----
  f16x2 m2[4];
  #pragma unroll
  for (int e = 0; e < 4; ++e) m2[e] = z2[e];
  #pragma unroll
  for (int tt = 1; tt < 16; ++tt)
    #pragma unroll
    for (int e = 0; e < 4; ++e)
      m2[e] = __builtin_elementwise_max(m2[e], z2[tt * 4 + e]);
  float m[4];
  #pragma unroll
  for (int e = 0; e < 4; ++e) m[e] = fmaxf((float)m2[e][0], (float)m2[e][1]);
  #pragma unroll
  for (int dm = 1; dm <= 8; dm <<= 1)
    #pragma unroll
    for (int e = 0; e < 4; ++e) m[e] = fmaxf(m[e], __shfl_xor(m[e], dm, 64));
  if (c == 0) {
    #pragma unroll
    for (int e = 0; e < 4; ++e) red[0][w][4 * g + e][0] = m[e];
  }
  __syncthreads();
  #pragma unroll
  for (int e = 0; e < 4; ++e) {
    const int r = 4 * g + e;
    m[e] = fmaxf(fmaxf(red[0][0][r][0], red[0][1][r][0]),
                 fmaxf(red[0][2][r][0], red[0][3][r][0]));
  }

  float tau[4];
  #pragma unroll
  for (int e = 0; e < 4; ++e) tau[e] = m[e] - 1.f;

  const f16x2 one2  = {(_Float16)1.f, (_Float16)1.f};
  const f16x2 zero2 = {(_Float16)0.f, (_Float16)0.f};

  // ---- Newton on f(tau)=sum clip(z-tau,0)^2 - 1 (packed f16, dot2 accum) ----
  #pragma unroll 1
  for (int it = 0; it < NIT; ++it) {
    const int pb = (it + 1) & 1;
    f16x2 tau2[4];
    #pragma unroll
    for (int e = 0; e < 4; ++e)
      tau2[e] = cvt_pk(tau[e], tau[e]);
    float S1[4] = {0.f, 0.f, 0.f, 0.f}, S2[4] = {0.f, 0.f, 0.f, 0.f};
    #pragma unroll
    for (int tt = 0; tt < 16; ++tt)
      #pragma unroll
      for (int e = 0; e < 4; ++e) {
        f16x2 d2 = z2[tt * 4 + e] - tau2[e];
        d2 = __builtin_elementwise_max(d2, zero2);
        S1[e] = FDOT2(d2, one2, S1[e]);
        S2[e] = FDOT2(d2, d2, S2[e]);
      }
    #pragma unroll
    for (int dm = 1; dm <= 8; dm <<= 1)
      #pragma unroll
      for (int e = 0; e < 4; ++e) {
        S1[e] += __shfl_xor(S1[e], dm, 64);
        S2[e] += __shfl_xor(S2[e], dm, 64);
      }
    if (c == 0) {
      #pragma unroll
      for (int e = 0; e < 4; ++e) {
        red[pb][w][4 * g + e][0] = S1[e];
        red[pb][w][4 * g + e][1] = S2[e];
      }
    }
    __syncthreads();
    #pragma unroll
    for (int e = 0; e < 4; ++e) {
      const int r = 4 * g + e;
      float s1 = red[pb][0][r][0] + red[pb][1][r][0] + red[pb][2][r][0] + red[pb][3][r][0];
      float s2 = red[pb][0][r][1] + red[pb][1][r][1] + red[pb][2][r][1] + red[pb][3][r][1];
      tau[e] = fminf(tau[e] + (s2 - 1.f) / (2.f * s1 + 1e-20f), m[e] - 0.01f);
    }
  }

  // ---- final p = clip(z-tau,0)^2, reuse z2 regs ----
  {
    f16x2 tau2[4];
    #pragma unroll
    for (int e = 0; e < 4; ++e)
      tau2[e] = cvt_pk(tau[e], tau[e]);
    #pragma unroll
    for (int tt = 0; tt < 16; ++tt)
      #pragma unroll
      for (int e = 0; e < 4; ++e) {
        f16x2 d2 = z2[tt * 4 + e] - tau2[e];
        d2 = __builtin_elementwise_max(d2, zero2);
        z2[tt * 4 + e] = d2 * d2;
      }
  }

  // ---- PV in two j-half phases (p_lds holds 16 x 1024) ----
  f32x4 oacc = {};
  if (w < 2) {          // phase A writers: j in [0,1024)
    #pragma unroll
    for (int tt = 0; tt < 16; ++tt)
      #pragma unroll
      for (int e = 0; e < 4; ++e) {
        const int row = 4 * g + e;
        const int col = (w << 9) + 32 * tt + c;
        p_lds[row * 1032 + col]      = z2[tt * 4 + e][0];
        p_lds[row * 1032 + col + 16] = z2[tt * 4 + e][1];
      }
  }
  __syncthreads();
  #pragma unroll
  for (int T = 0; T < 32; ++T) {
    f16x8 pa = *(f16x8*)&p_lds[c * 1032 + 32 * T + 8 * g];
    f16x8 vb = *(const f16x8*)(VT + (size_t)(16 * w + c) * N_ + 32 * T + 8 * g);
    oacc = MFMA16(pa, vb, oacc);
  }
  __syncthreads();
  if (w >= 2) {         // phase B writers: j in [1024,2048)
    #pragma unroll
    for (int tt = 0; tt < 16; ++tt)
      #pragma unroll
      for (int e = 0; e < 4; ++e) {
        const int row = 4 * g + e;
        const int col = ((w - 2) << 9) + 32 * tt + c;
        p_lds[row * 1032 + col]      = z2[tt * 4 + e][0];
        p_lds[row * 1032 + col + 16] = z2[tt * 4 + e][1];
      }
  }
  __syncthreads();
  #pragma unroll
  for (int T = 0; T < 32; ++T) {
    f16x8 pa = *(f16x8*)&p_lds[c * 1032 + 32 * T + 8 * g];
    f16x8 vb = *(const f16x8*)(VT + (size_t)(16 * w + c) * N_ + 1024 + 32 * T + 8 * g);
    oacc = MFMA16(pa, vb, oacc);
  }

  const int b = bh >> 3, h = bh & 7;
  #pragma unroll
  for (int e = 0; e < 4; ++e)
    o[((size_t)b * N_ + n0 + 4 * g + e) * C_ + h * 64 + 16 * w + c] = oacc[e];
}

// ---------------- ln_res: LayerNorm(o)+residual, LDS-transposed x -------------
__global__ __launch_bounds__(256) void ln_res(
    const float* __restrict__ o, const float* __restrict__ x,
    const float* __restrict__ a2, const float* __restrict__ b2,
    float* __restrict__ out)
{
  const int row0 = blockIdx.x * 8;            // 8 rows per block
  const int b = row0 >> 11, nl = row0 & (N_ - 1);
  const int t = threadIdx.x;
  __shared__ float xres[8][516];
  {
    #pragma unroll
    for (int rep = 0; rep < 2; ++rep) {
      const int cc = t + rep * 256;
      const float* xp = x + ((size_t)(b * C_ + cc)) * N_ + nl;
      float4 u0 = *(const float4*)(xp);
      float4 u1 = *(const float4*)(xp + 4);
      xres[0][cc] = u0.x; xres[1][cc] = u0.y; xres[2][cc] = u0.z; xres[3][cc] = u0.w;
      xres[4][cc] = u1.x; xres[5][cc] = u1.y; xres[6][cc] = u1.z; xres[7][cc] = u1.w;
    }
  }
  __syncthreads();
  const int w = t >> 6, lane = t & 63;
  #pragma unroll
  for (int rr = 0; rr < 2; ++rr) {
    const int r = w * 2 + rr;
    const size_t row = (size_t)row0 + r;
    float v[8];
    #pragma unroll
    for (int i = 0; i < 8; ++i) v[i] = o[row * C_ + lane + 64 * i];
    float s = 0.f, ss = 0.f;
    #pragma unroll
    for (int i = 0; i < 8; ++i) { s += v[i]; ss = fmaf(v[i], v[i], ss); }
    #pragma unroll
    for (int dm = 1; dm <= 32; dm <<= 1) {
      s  += __shfl_xor(s, dm, 64);
      ss += __shfl_xor(ss, dm, 64);
    }
    const float mean = s * (1.f / C_);
    float var = (ss - (float)C_ * mean * mean) * (1.f / (C_ - 1));
    var = fmaxf(var, 0.f);
    const float rd = 1.f / (sqrtf(var) + 1e-6f);
    #pragma unroll
    for (int i = 0; i < 8; ++i) {
      const int cc = lane + 64 * i;
      out[row * C_ + cc] = a2[cc] * (v[i] - mean) * rd + b2[cc] + xres[r][cc];
    }
  }
}

// ---------------- launch ------------------------------------------------------
extern "C" void kernel_launch(void* const* d_in, const int* in_sizes, int n_in,
                              void* d_out, int out_size, void* d_ws, size_t ws_size,
                              hipStream_t stream)
{
  const float* x  = (const float*)d_in[0];
  const float* Wq = (const float*)d_in[1];
  const float* bq = (const float*)d_in[2];
  const float* Wk = (const float*)d_in[3];
  const float* bk = (const float*)d_in[4];
  const float* Wv = (const float*)d_in[5];
  const float* bv = (const float*)d_in[6];
  const float* a2 = (const float*)d_in[7];
  const float* b2 = (const float*)d_in[8];

  const size_t HEADSZ = (size_t)BH_ * N_ * DK_;   // 2,097,152 elems
  f16* q16  = (f16*)d_ws;                         // 4 MB
  f16* k16  = q16 + HEADSZ;                       // 4 MB
  f16* vT16 = k16 + HEADSZ;                       // 4 MB (ws total = 12 MB, proven)

  // xT16 + W16 live in d_out (8 MB): dead before attn overwrites it with o.
  f16* xT16 = (f16*)d_out;                        // 4 MB (B*N*C f16)
  f16* W16  = xT16 + (size_t)B_ * N_ * C_;        // 1.5 MB
  float* o  = (float*)d_out;

  prep_x  <<<dim3(32, 8, 2),  256, 0, stream>>>(x, xT16);
  wconv   <<<dim3(128, 3),    256, 0, stream>>>(Wq, Wk, Wv, W16);
  qkv_mfma<<<dim3(32, 8, 6),  256, 0, stream>>>(xT16, W16, bq, bk, bv, q16, k16, vT16);
  attn    <<<dim3(N_ / 16, BH_), 256, 0, stream>>>(q16, k16, vT16, o);
  ln_res  <<<dim3(512),       256, 0, stream>>>(o, x, a2, b2, (float*)d_out);
}

// Round 6
// 231.644 us; speedup vs baseline: 2.3468x; 1.2248x over previous
//
#include <hip/hip_runtime.h>

typedef _Float16 f16;
typedef _Float16 f16x2 __attribute__((ext_vector_type(2)));
typedef _Float16 f16x4 __attribute__((ext_vector_type(4)));
typedef _Float16 f16x8 __attribute__((ext_vector_type(8)));
typedef float    f32x4 __attribute__((ext_vector_type(4)));

#define B_  2
#define C_  512
#define N_  2048
#define H_  8
#define DK_ 64
#define BH_ 16
#define NIT 8

static __device__ __forceinline__ f16x2 cvt_pk(float a, float b) {
  return __builtin_bit_cast(f16x2, __builtin_amdgcn_cvt_pkrtz(a, b));
}

#if defined(__has_builtin)
#if __has_builtin(__builtin_amdgcn_fdot2)
#define FDOT2(a,b,c) __builtin_amdgcn_fdot2((a),(b),(c),false)
#endif
#endif
#ifndef FDOT2
static __device__ __forceinline__ float FDOT2(f16x2 a, f16x2 b, float c) {
  return c + (float)a[0]*(float)b[0] + (float)a[1]*(float)b[1];
}
#endif

#define MFMA16(a,b,acc) __builtin_amdgcn_mfma_f32_16x16x32_f16((a),(b),(acc),0,0,0)

// ---------------- prep_x: x (b,m,n) fp32 -> xT16 (b,n,m) f16 ------------------
__global__ __launch_bounds__(256) void prep_x(const float* __restrict__ x,
                                              f16* __restrict__ xT)
{
  const int nt = blockIdx.x, mt = blockIdx.y, b = blockIdx.z;
  const int n0 = nt * 64, m0 = mt * 64;
  __shared__ float tile[64][65];
  const int t = threadIdx.x;
  {
    const int ml = t >> 2, nc = (t & 3) * 16;
    const float* src = x + ((size_t)(b * C_ + m0 + ml)) * N_ + n0 + nc;
    *(float4*)&tile[ml][nc]      = *(const float4*)(src);
    *(float4*)&tile[ml][nc + 4]  = *(const float4*)(src + 4);
    *(float4*)&tile[ml][nc + 8]  = *(const float4*)(src + 8);
    *(float4*)&tile[ml][nc + 12] = *(const float4*)(src + 12);
  }
  __syncthreads();
  {
    const int nl = t >> 2, mc = (t & 3) * 16;
    f16x8 o0, o1;
    #pragma unroll
    for (int i = 0; i < 8; ++i) {
      o0[i] = (f16)tile[mc + i][nl];
      o1[i] = (f16)tile[mc + 8 + i][nl];
    }
    f16* dst = xT + ((size_t)(b * N_ + n0 + nl)) * C_ + m0 + mc;
    *(f16x8*)(dst)     = o0;
    *(f16x8*)(dst + 8) = o1;
  }
}

// ---------------- qkv_lds: LDS-staged GEMM, 64n x 64c tile, BK=64 -------------
// A = xT16 (f16), B = W fp32 (cvt in stager). XOR-swizzled LDS (chunk^= row&7).
// mat 0/1 (Q,K): store (b,h,n,d); mat 2 (V): store transposed (b,c,n).
// q16 pre-scaled by 1/16.
__global__ __launch_bounds__(256) void qkv_lds(
    const f16* __restrict__ xT,
    const float* __restrict__ Wq, const float* __restrict__ Wk,
    const float* __restrict__ Wv,
    const float* __restrict__ bq, const float* __restrict__ bk,
    const float* __restrict__ bv,
    f16* __restrict__ q16, f16* __restrict__ k16, f16* __restrict__ vT16)
{
  const int nt = blockIdx.x, ctb = blockIdx.y, z = blockIdx.z;
  const int b = z / 3, mat = z % 3;
  const float* W    = (mat == 0) ? Wq : (mat == 1) ? Wk : Wv;
  const float* bias = (mat == 0) ? bq : (mat == 1) ? bk : bv;
  const int n0 = nt * 64, c0 = ctb * 64;

  __shared__ f16 As[64 * 64];
  __shared__ f16 Bs[64 * 64];

  const int t = threadIdx.x, w = t >> 6, lane = t & 63;
  const int c = lane & 15, g = lane >> 4;

  // staging coords (constant per thread): chunk q -> row r, phys slot d
  const int rA0 = t >> 3,        dA0 = t & 7;           // A rows 0..31
  const int rA1 = (t + 256) >> 3, dA1 = t & 7;          // A rows 32..63
  const f16* aSrc0 = xT + (size_t)(b * N_ + n0 + rA0) * C_ + 8 * (dA0 ^ (rA0 & 7));
  const f16* aSrc1 = xT + (size_t)(b * N_ + n0 + rA1) * C_ + 8 * (dA1 ^ (rA1 & 7));
  const float* wSrc0 = W + (size_t)(c0 + rA0) * C_ + 8 * (dA0 ^ (rA0 & 7));
  const float* wSrc1 = W + (size_t)(c0 + rA1) * C_ + 8 * (dA1 ^ (rA1 & 7));

  f32x4 acc[4] = {};
  #pragma unroll 1
  for (int k0 = 0; k0 < C_; k0 += 64) {
    // ---- stage A (f16 direct) ----
    *(f16x8*)&As[rA0 * 64 + 8 * dA0] = *(const f16x8*)(aSrc0 + k0);
    *(f16x8*)&As[rA1 * 64 + 8 * dA1] = *(const f16x8*)(aSrc1 + k0);
    // ---- stage B (fp32 -> f16) ----
    {
      float4 u0 = *(const float4*)(wSrc0 + k0);
      float4 u1 = *(const float4*)(wSrc0 + k0 + 4);
      union { f16x8 v8; f16x2 v2[4]; } u;
      u.v2[0] = cvt_pk(u0.x, u0.y); u.v2[1] = cvt_pk(u0.z, u0.w);
      u.v2[2] = cvt_pk(u1.x, u1.y); u.v2[3] = cvt_pk(u1.z, u1.w);
      *(f16x8*)&Bs[rA0 * 64 + 8 * dA0] = u.v8;
    }
    {
      float4 u0 = *(const float4*)(wSrc1 + k0);
      float4 u1 = *(const float4*)(wSrc1 + k0 + 4);
      union { f16x8 v8; f16x2 v2[4]; } u;
      u.v2[0] = cvt_pk(u0.x, u0.y); u.v2[1] = cvt_pk(u0.z, u0.w);
      u.v2[2] = cvt_pk(u1.x, u1.y); u.v2[3] = cvt_pk(u1.z, u1.w);
      *(f16x8*)&Bs[rA1 * 64 + 8 * dA1] = u.v8;
    }
    __syncthreads();
    // ---- compute ----
    const int ar = w * 16 + c;
    f16x8 a0 = *(const f16x8*)&As[ar * 64 + 8 * (g ^ (ar & 7))];
    f16x8 a1 = *(const f16x8*)&As[ar * 64 + 8 * ((4 + g) ^ (ar & 7))];
    #pragma unroll
    for (int ct = 0; ct < 4; ++ct) {
      const int br = ct * 16 + c;
      f16x8 b0 = *(const f16x8*)&Bs[br * 64 + 8 * (g ^ (br & 7))];
      f16x8 b1 = *(const f16x8*)&Bs[br * 64 + 8 * ((4 + g) ^ (br & 7))];
      acc[ct] = MFMA16(a0, b0, acc[ct]);
      acc[ct] = MFMA16(a1, b1, acc[ct]);
    }
    __syncthreads();
  }

  // ---- epilogue (identical structure to round 5) ----
  const int nOut = n0 + w * 16 + 4 * g;            // + e
  #pragma unroll
  for (int ct = 0; ct < 4; ++ct) {
    const int ccol = c0 + ct * 16 + c;
    const float bb = bias[ccol];
    if (mat == 2) {
      f16x4 pk;
      #pragma unroll
      for (int e = 0; e < 4; ++e) pk[e] = (f16)(acc[ct][e] + bb);
      *(f16x4*)(vT16 + ((size_t)(b * C_ + ccol)) * N_ + nOut) = pk;
    } else {
      const int h = ccol >> 6, d = ccol & 63;
      f16* out = (mat == 0) ? q16 : k16;
      const float sc = (mat == 0) ? 0.0625f : 1.0f;
      #pragma unroll
      for (int e = 0; e < 4; ++e)
        out[((size_t)((b * H_ + h) * N_ + nOut + e)) * DK_ + d] =
            (f16)((acc[ct][e] + bb) * sc);
    }
  }
}

// ---------------- attn: energy(MFMA) + packed-f16 Newton entmax1.5 + PV -------
// 16 q-rows/block, 4 waves x 512-j strips. z kept as 64 f16x2 regs (j, j+16).
__global__ __launch_bounds__(256, 4) void attn(
    const f16* __restrict__ q16, const f16* __restrict__ k16,
    const f16* __restrict__ vT16, float* __restrict__ o)
{
  const int bh = blockIdx.y;
  const int n0 = blockIdx.x * 16;
  const int t = threadIdx.x;
  const int w = t >> 6, lane = t & 63;
  const int c = lane & 15, g = lane >> 4;

  __shared__ f16 p_lds[16 * 1032];        // [row][j-half], pad 8
  __shared__ float red[2][4][16][2];      // dbuf cross-wave scratch

  const f16* Q  = q16  + (size_t)bh * N_ * DK_;
  const f16* K  = k16  + (size_t)bh * N_ * DK_;
  const f16* VT = vT16 + (size_t)bh * DK_ * N_;

  f16x8 qa0 = *(const f16x8*)(Q + (size_t)(n0 + c) * DK_ + 8 * g);
  f16x8 qa1 = *(const f16x8*)(Q + (size_t)(n0 + c) * DK_ + 32 + 8 * g);

  const int jbase = w * 512;

  // ---- energy -> z2 f16 pairs (z = q.k/16 via pre-scaled q) ----
  f16x2 z2[64];
  #pragma unroll
  for (int tt = 0; tt < 16; ++tt) {
    const f16* kp0 = K + (size_t)(jbase + 32 * tt + c) * DK_ + 8 * g;
    f16x8 kb00 = *(const f16x8*)(kp0);
    f16x8 kb01 = *(const f16x8*)(kp0 + 32);
    f16x8 kb10 = *(const f16x8*)(kp0 + 16 * DK_);
    f16x8 kb11 = *(const f16x8*)(kp0 + 16 * DK_ + 32);
    f32x4 a0 = {}, a1 = {};
    a0 = MFMA16(qa0, kb00, a0);
    a0 = MFMA16(qa1, kb01, a0);
    a1 = MFMA16(qa0, kb10, a1);
    a1 = MFMA16(qa1, kb11, a1);
    #pragma unroll
    for (int e = 0; e < 4; ++e)
      z2[tt * 4 + e] = cvt_pk(a0[e], a1[e]);
  }

  // ---- row max ----
  f16x2 m2[4];
  #pragma unroll
  for (int e = 0; e < 4; ++e) m2[e] = z2[e];
  #pragma unroll
  for (int tt = 1; tt < 16; ++tt)
    #pragma unroll
    for (int e = 0; e < 4; ++e)
      m2[e] = __builtin_elementwise_max(m2[e], z2[tt * 4 + e]);
  float m[4];
  #pragma unroll
  for (int e = 0; e < 4; ++e) m[e] = fmaxf((float)m2[e][0], (float)m2[e][1]);
  #pragma unroll
  for (int dm = 1; dm <= 8; dm <<= 1)
    #pragma unroll
    for (int e = 0; e < 4; ++e) m[e] = fmaxf(m[e], __shfl_xor(m[e], dm, 64));
  if (c == 0) {
    #pragma unroll
    for (int e = 0; e < 4; ++e) red[0][w][4 * g + e][0] = m[e];
  }
  __syncthreads();
  #pragma unroll
  for (int e = 0; e < 4; ++e) {
    const int r = 4 * g + e;
    m[e] = fmaxf(fmaxf(red[0][0][r][0], red[0][1][r][0]),
                 fmaxf(red[0][2][r][0], red[0][3][r][0]));
  }

  float tau[4];
  #pragma unroll
  for (int e = 0; e < 4; ++e) tau[e] = m[e] - 1.f;

  const f16x2 one2  = {(_Float16)1.f, (_Float16)1.f};
  const f16x2 zero2 = {(_Float16)0.f, (_Float16)0.f};

  // ---- Newton on f(tau)=sum clip(z-tau,0)^2 - 1 (packed f16, dot2 accum) ----
  #pragma unroll 1
  for (int it = 0; it < NIT; ++it) {
    const int pb = (it + 1) & 1;
    f16x2 tau2[4];
    #pragma unroll
    for (int e = 0; e < 4; ++e)
      tau2[e] = cvt_pk(tau[e], tau[e]);
    float S1[4] = {0.f, 0.f, 0.f, 0.f}, S2[4] = {0.f, 0.f, 0.f, 0.f};
    #pragma unroll
    for (int tt = 0; tt < 16; ++tt)
      #pragma unroll
      for (int e = 0; e < 4; ++e) {
        f16x2 d2 = z2[tt * 4 + e] - tau2[e];
        d2 = __builtin_elementwise_max(d2, zero2);
        S1[e] = FDOT2(d2, one2, S1[e]);
        S2[e] = FDOT2(d2, d2, S2[e]);
      }
    #pragma unroll
    for (int dm = 1; dm <= 8; dm <<= 1)
      #pragma unroll
      for (int e = 0; e < 4; ++e) {
        S1[e] += __shfl_xor(S1[e], dm, 64);
        S2[e] += __shfl_xor(S2[e], dm, 64);
      }
    if (c == 0) {
      #pragma unroll
      for (int e = 0; e < 4; ++e) {
        red[pb][w][4 * g + e][0] = S1[e];
        red[pb][w][4 * g + e][1] = S2[e];
      }
    }
    __syncthreads();
    #pragma unroll
    for (int e = 0; e < 4; ++e) {
      const int r = 4 * g + e;
      float s1 = red[pb][0][r][0] + red[pb][1][r][0] + red[pb][2][r][0] + red[pb][3][r][0];
      float s2 = red[pb][0][r][1] + red[pb][1][r][1] + red[pb][2][r][1] + red[pb][3][r][1];
      tau[e] = fminf(tau[e] + (s2 - 1.f) / (2.f * s1 + 1e-20f), m[e] - 0.01f);
    }
  }

  // ---- final p = clip(z-tau,0)^2, reuse z2 regs ----
  {
    f16x2 tau2[4];
    #pragma unroll
    for (int e = 0; e < 4; ++e)
      tau2[e] = cvt_pk(tau[e], tau[e]);
    #pragma unroll
    for (int tt = 0; tt < 16; ++tt)
      #pragma unroll
      for (int e = 0; e < 4; ++e) {
        f16x2 d2 = z2[tt * 4 + e] - tau2[e];
        d2 = __builtin_elementwise_max(d2, zero2);
        z2[tt * 4 + e] = d2 * d2;
      }
  }

  // ---- PV in two j-half phases (p_lds holds 16 x 1024) ----
  f32x4 oacc = {};
  if (w < 2) {          // phase A writers: j in [0,1024)
    #pragma unroll
    for (int tt = 0; tt < 16; ++tt)
      #pragma unroll
      for (int e = 0; e < 4; ++e) {
        const int row = 4 * g + e;
        const int col = (w << 9) + 32 * tt + c;
        p_lds[row * 1032 + col]      = z2[tt * 4 + e][0];
        p_lds[row * 1032 + col + 16] = z2[tt * 4 + e][1];
      }
  }
  __syncthreads();
  #pragma unroll
  for (int T = 0; T < 32; ++T) {
    f16x8 pa = *(f16x8*)&p_lds[c * 1032 + 32 * T + 8 * g];
    f16x8 vb = *(const f16x8*)(VT + (size_t)(16 * w + c) * N_ + 32 * T + 8 * g);
    oacc = MFMA16(pa, vb, oacc);
  }
  __syncthreads();
  if (w >= 2) {         // phase B writers: j in [1024,2048)
    #pragma unroll
    for (int tt = 0; tt < 16; ++tt)
      #pragma unroll
      for (int e = 0; e < 4; ++e) {
        const int row = 4 * g + e;
        const int col = ((w - 2) << 9) + 32 * tt + c;
        p_lds[row * 1032 + col]      = z2[tt * 4 + e][0];
        p_lds[row * 1032 + col + 16] = z2[tt * 4 + e][1];
      }
  }
  __syncthreads();
  #pragma unroll
  for (int T = 0; T < 32; ++T) {
    f16x8 pa = *(f16x8*)&p_lds[c * 1032 + 32 * T + 8 * g];
    f16x8 vb = *(const f16x8*)(VT + (size_t)(16 * w + c) * N_ + 1024 + 32 * T + 8 * g);
    oacc = MFMA16(pa, vb, oacc);
  }

  const int b = bh >> 3, h = bh & 7;
  #pragma unroll
  for (int e = 0; e < 4; ++e)
    o[((size_t)b * N_ + n0 + 4 * g + e) * C_ + h * 64 + 16 * w + c] = oacc[e];
}

// ---------------- ln_res: LayerNorm(o)+residual, LDS-transposed x -------------
__global__ __launch_bounds__(256) void ln_res(
    const float* __restrict__ o, const float* __restrict__ x,
    const float* __restrict__ a2, const float* __restrict__ b2,
    float* __restrict__ out)
{
  const int row0 = blockIdx.x * 8;            // 8 rows per block
  const int b = row0 >> 11, nl = row0 & (N_ - 1);
  const int t = threadIdx.x;
  __shared__ float xres[8][516];
  {
    #pragma unroll
    for (int rep = 0; rep < 2; ++rep) {
      const int cc = t + rep * 256;
      const float* xp = x + ((size_t)(b * C_ + cc)) * N_ + nl;
      float4 u0 = *(const float4*)(xp);
      float4 u1 = *(const float4*)(xp + 4);
      xres[0][cc] = u0.x; xres[1][cc] = u0.y; xres[2][cc] = u0.z; xres[3][cc] = u0.w;
      xres[4][cc] = u1.x; xres[5][cc] = u1.y; xres[6][cc] = u1.z; xres[7][cc] = u1.w;
    }
  }
  __syncthreads();
  const int w = t >> 6, lane = t & 63;
  #pragma unroll
  for (int rr = 0; rr < 2; ++rr) {
    const int r = w * 2 + rr;
    const size_t row = (size_t)row0 + r;
    float v[8];
    #pragma unroll
    for (int i = 0; i < 8; ++i) v[i] = o[row * C_ + lane + 64 * i];
    float s = 0.f, ss = 0.f;
    #pragma unroll
    for (int i = 0; i < 8; ++i) { s += v[i]; ss = fmaf(v[i], v[i], ss); }
    #pragma unroll
    for (int dm = 1; dm <= 32; dm <<= 1) {
      s  += __shfl_xor(s, dm, 64);
      ss += __shfl_xor(ss, dm, 64);
    }
    const float mean = s * (1.f / C_);
    float var = (ss - (float)C_ * mean * mean) * (1.f / (C_ - 1));
    var = fmaxf(var, 0.f);
    const float rd = 1.f / (sqrtf(var) + 1e-6f);
    #pragma unroll
    for (int i = 0; i < 8; ++i) {
      const int cc = lane + 64 * i;
      out[row * C_ + cc] = a2[cc] * (v[i] - mean) * rd + b2[cc] + xres[r][cc];
    }
  }
}

// ---------------- launch ------------------------------------------------------
extern "C" void kernel_launch(void* const* d_in, const int* in_sizes, int n_in,
                              void* d_out, int out_size, void* d_ws, size_t ws_size,
                              hipStream_t stream)
{
  const float* x  = (const float*)d_in[0];
  const float* Wq = (const float*)d_in[1];
  const float* bq = (const float*)d_in[2];
  const float* Wk = (const float*)d_in[3];
  const float* bk = (const float*)d_in[4];
  const float* Wv = (const float*)d_in[5];
  const float* bv = (const float*)d_in[6];
  const float* a2 = (const float*)d_in[7];
  const float* b2 = (const float*)d_in[8];

  const size_t HEADSZ = (size_t)BH_ * N_ * DK_;   // 2,097,152 elems
  f16* q16  = (f16*)d_ws;                         // 4 MB
  f16* k16  = q16 + HEADSZ;                       // 4 MB
  f16* vT16 = k16 + HEADSZ;                       // 4 MB (ws total = 12 MB, proven)

  // xT16 lives in d_out (8 MB): dead before attn overwrites it with o.
  f16* xT16 = (f16*)d_out;                        // 4 MB (B*N*C f16)
  float* o  = (float*)d_out;

  prep_x <<<dim3(32, 8, 2),  256, 0, stream>>>(x, xT16);
  qkv_lds<<<dim3(32, 8, 6),  256, 0, stream>>>(xT16, Wq, Wk, Wv, bq, bk, bv,
                                               q16, k16, vT16);
  attn   <<<dim3(N_ / 16, BH_), 256, 0, stream>>>(q16, k16, vT16, o);
  ln_res <<<dim3(512),       256, 0, stream>>>(o, x, a2, b2, (float*)d_out);
}